// Round 8
// baseline (219.561 us; speedup 1.0000x reference)
//
#include <hip/hip_runtime.h>
#include <float.h>

#define NT 32768
#define DIM 2048
#define NE 64
#define TAU 1e-3f

typedef __attribute__((ext_vector_type(8))) short short8;
typedef __attribute__((ext_vector_type(4))) float f32x4;

__device__ __forceinline__ unsigned short f2bf(float f) {
    unsigned u = __float_as_uint(f);
    u += 0x7fffu + ((u >> 16) & 1u);          // RNE
    return (unsigned short)(u >> 16);
}
__device__ __forceinline__ float bf2f(unsigned short h) {
    return __uint_as_float(((unsigned)h) << 16);
}

// Split gw into hi/lo bf16 planes (row-major [64][2048]); zero the flag counter.
__global__ __launch_bounds__(256)
void prep_w(const float* __restrict__ gw, unsigned short* __restrict__ wh,
            unsigned short* __restrict__ wl, int* __restrict__ cnt) {
    int i = (blockIdx.x * 256 + threadIdx.x) * 4;
    float4 v = *(const float4*)(gw + i);
    unsigned short h0 = f2bf(v.x), h1 = f2bf(v.y), h2 = f2bf(v.z), h3 = f2bf(v.w);
    *(ushort4*)(wh + i) = make_ushort4(h0, h1, h2, h3);
    *(ushort4*)(wl + i) = make_ushort4(f2bf(v.x - bf2f(h0)), f2bf(v.y - bf2f(h1)),
                                       f2bf(v.z - bf2f(h2)), f2bf(v.w - bf2f(h3)));
    if (blockIdx.x == 0 && threadIdx.x == 0) *cnt = 0;
}

__global__ __launch_bounds__(256, 4)
void router_mfma(const float* __restrict__ x,
                 const unsigned short* __restrict__ wh,
                 const unsigned short* __restrict__ wl,
                 float* __restrict__ out,
                 int* __restrict__ cnt, int* __restrict__ list) {
    __shared__ float red[4][16][68];              // [kq][token][expert(+pad)]

    const int tid  = threadIdx.x;
    const int lane = tid & 63;
    const int kq   = tid >> 6;                    // wave == k-quarter
    const int sub  = lane & 15;                   // A-row (token) / B-col (expert)
    const int kg   = lane >> 4;                   // k-octet selector
    const int t0   = blockIdx.x * 16;

    const float* xp = x + (size_t)(t0 + sub) * DIM + kq * 512 + kg * 8;
    const unsigned short* whp = wh + (size_t)sub * DIM + kq * 512 + kg * 8;
    const unsigned short* wlp = wl + (size_t)sub * DIM + kq * 512 + kg * 8;

    f32x4 acc[4];
#pragma unroll
    for (int et = 0; et < 4; ++et)
#pragma unroll
        for (int j = 0; j < 4; ++j) acc[et][j] = 0.f;

#pragma unroll 2
    for (int ks = 0; ks < 16; ++ks) {
        const int ko = ks * 32;
        // x: 32 B/lane, two b128 loads (contiguous 128 B per 4-lane kg group)
        float4 a0 = *(const float4*)(xp + ko);
        float4 a1 = *(const float4*)(xp + ko + 4);
        float xf[8] = {a0.x, a0.y, a0.z, a0.w, a1.x, a1.y, a1.z, a1.w};
        short8 ah, al;
#pragma unroll
        for (int j = 0; j < 8; ++j) {
            unsigned short h = f2bf(xf[j]);
            ah[j] = (short)h;
            al[j] = (short)f2bf(xf[j] - bf2f(h));
        }
#pragma unroll
        for (int et = 0; et < 4; ++et) {
            short8 bhv = *(const short8*)(whp + (size_t)et * 16 * DIM + ko);
            short8 blv = *(const short8*)(wlp + (size_t)et * 16 * DIM + ko);
            acc[et] = __builtin_amdgcn_mfma_f32_16x16x32_bf16(ah, bhv, acc[et], 0, 0, 0);
            acc[et] = __builtin_amdgcn_mfma_f32_16x16x32_bf16(ah, blv, acc[et], 0, 0, 0);
            acc[et] = __builtin_amdgcn_mfma_f32_16x16x32_bf16(al, bhv, acc[et], 0, 0, 0);
        }
    }

    // deposit partials: D layout col(expert)=lane&15, row(token)=(lane>>4)*4+r
#pragma unroll
    for (int et = 0; et < 4; ++et)
#pragma unroll
        for (int r = 0; r < 4; ++r)
            red[kq][kg * 4 + r][et * 16 + sub] = acc[et][r];
    __syncthreads();

    // ---- epilogue: 16 threads per token (consecutive lanes), 4 experts each ----
    float* mout = out;
    float* wout = out + (size_t)NT * NE;
    float* iout = wout + (size_t)NT * 2;

    const int t   = tid >> 4;                     // local token 0..15
    const int s   = tid & 15;                     // 4-expert segment
    const int tok = t0 + t;

    float4 p0 = *(const float4*)&red[0][t][s * 4];
    float4 p1 = *(const float4*)&red[1][t][s * 4];
    float4 p2 = *(const float4*)&red[2][t][s * 4];
    float4 p3 = *(const float4*)&red[3][t][s * 4];
    float vv[4];
    vv[0] = ((p0.x + p1.x) + p2.x) + p3.x;
    vv[1] = ((p0.y + p1.y) + p2.y) + p3.y;
    vv[2] = ((p0.z + p1.z) + p2.z) + p3.z;
    vv[3] = ((p0.w + p1.w) + p2.w) + p3.w;

    float m1 = -FLT_MAX, m2 = -FLT_MAX, m3 = -FLT_MAX;
    int   i1 = NE, i2 = NE, i3 = NE;
    auto ins = [&](float v, int e) {
        bool b1 = (v > m1) || (v == m1 && e < i1);
        bool b2 = (v > m2) || (v == m2 && e < i2);
        bool b3 = (v > m3) || (v == m3 && e < i3);
        if (b1)      { m3 = m2; i3 = i2; m2 = m1; i2 = i1; m1 = v; i1 = e; }
        else if (b2) { m3 = m2; i3 = i2; m2 = v; i2 = e; }
        else if (b3) { m3 = v; i3 = e; }
    };
#pragma unroll
    for (int j = 0; j < 4; ++j) ins(vv[j], s * 4 + j);
#pragma unroll
    for (int off = 1; off <= 8; off <<= 1) {      // merge across the 16-lane group
        float om1 = __shfl_xor(m1, off, 64); int oi1 = __shfl_xor(i1, off, 64);
        float om2 = __shfl_xor(m2, off, 64); int oi2 = __shfl_xor(i2, off, 64);
        float om3 = __shfl_xor(m3, off, 64); int oi3 = __shfl_xor(i3, off, 64);
        ins(om1, oi1); ins(om2, oi2); ins(om3, oi3);
    }

    float ed  = expf(m2 - m1);
    float inv = 1.f / (1.f + ed);

    float4 mv;
    mv.x = (s * 4     == i1 || s * 4     == i2) ? 1.f : 0.f;
    mv.y = (s * 4 + 1 == i1 || s * 4 + 1 == i2) ? 1.f : 0.f;
    mv.z = (s * 4 + 2 == i1 || s * 4 + 2 == i2) ? 1.f : 0.f;
    mv.w = (s * 4 + 3 == i1 || s * 4 + 3 == i2) ? 1.f : 0.f;
    *(float4*)(mout + (size_t)tok * NE + s * 4) = mv;

    if (s == 0) {
        *(float2*)(wout + 2 * tok) = make_float2(inv, ed * inv);
        *(float2*)(iout + 2 * tok) = make_float2((float)i1, (float)i2);
        if ((m1 - m2 < TAU) || (m2 - m3 < TAU)) {
            int slot = atomicAdd(cnt, 1);
            list[slot] = tok;
        }
    }
}

// Exact fp32 recompute of flagged (near-tie) tokens; overwrites their outputs.
__global__ __launch_bounds__(256)
void repair(const float* __restrict__ x, const float* __restrict__ gw,
            float* __restrict__ out, const int* __restrict__ cnt,
            const int* __restrict__ list) {
    __shared__ float red[64][5];
    const int n   = *cnt;
    const int tid = threadIdx.x;
    const int e   = tid & 63, q = tid >> 6;     // expert, k-quarter

    float* mout = out;
    float* wout = out + (size_t)NT * NE;
    float* iout = wout + (size_t)NT * 2;

    for (int i = blockIdx.x; i < n; i += gridDim.x) {
        const int tok = list[i];
        const float* xr = x + (size_t)tok * DIM + q * 512;
        const float* wr = gw + (size_t)e * DIM + q * 512;
        float a = 0.f;
        for (int j = 0; j < 512; j += 4) {
            float4 xv = *(const float4*)(xr + j);
            float4 wv = *(const float4*)(wr + j);
            a = fmaf(xv.x, wv.x, a); a = fmaf(xv.y, wv.y, a);
            a = fmaf(xv.z, wv.z, a); a = fmaf(xv.w, wv.w, a);
        }
        red[e][q] = a;
        __syncthreads();
        if (tid < 64) {
            float v = ((red[e][0] + red[e][1]) + red[e][2]) + red[e][3];
            float m1 = v, m2 = -FLT_MAX; int i1 = e, i2 = NE;
#pragma unroll
            for (int off = 1; off <= 32; off <<= 1) {
                float om1 = __shfl_xor(m1, off, 64); int oi1 = __shfl_xor(i1, off, 64);
                float om2 = __shfl_xor(m2, off, 64); int oi2 = __shfl_xor(i2, off, 64);
                bool selfFirst = (m1 > om1) || (m1 == om1 && i1 < oi1);
                if (selfFirst) {
                    if (!((m2 > om1) || (m2 == om1 && i2 < oi1))) { m2 = om1; i2 = oi1; }
                } else {
                    bool c = (m1 > om2) || (m1 == om2 && i1 < oi2);
                    if (c) { m2 = m1; i2 = i1; } else { m2 = om2; i2 = oi2; }
                    m1 = om1; i1 = oi1;
                }
            }
            float ed  = expf(m2 - m1);
            float inv = 1.f / (1.f + ed);
            mout[(size_t)tok * NE + e] = (e == i1 || e == i2) ? 1.f : 0.f;
            if (e == 0) {
                *(float2*)(wout + 2 * tok) = make_float2(inv, ed * inv);
                *(float2*)(iout + 2 * tok) = make_float2((float)i1, (float)i2);
            }
        }
        __syncthreads();
    }
}

extern "C" void kernel_launch(void* const* d_in, const int* in_sizes, int n_in,
                              void* d_out, int out_size, void* d_ws, size_t ws_size,
                              hipStream_t stream) {
    const float* x  = (const float*)d_in[0];
    const float* gw = (const float*)d_in[1];
    float* out = (float*)d_out;

    unsigned short* wh = (unsigned short*)d_ws;          // 256 KB
    unsigned short* wl = wh + (size_t)NE * DIM;          // 256 KB
    int* cnt  = (int*)(wl + (size_t)NE * DIM);           // 4 B
    int* list = cnt + 1;                                 // 128 KB

    prep_w<<<dim3(128), dim3(256), 0, stream>>>(gw, wh, wl, cnt);
    router_mfma<<<dim3(NT / 16), dim3(256), 0, stream>>>(x, wh, wl, out, cnt, list);
    repair<<<dim3(256), dim3(256), 0, stream>>>(x, gw, out, cnt, list);
}

// Round 9
// 129.714 us; speedup vs baseline: 1.6926x; 1.6926x over previous
//
#include <hip/hip_runtime.h>
#include <float.h>

#define NT 32768
#define DIM 2048
#define NE 64
#define TAU 1e-3f
#define CHUNK 256                 // k per staged chunk
#define NCH (DIM / CHUNK)         // 8 chunks

typedef __attribute__((ext_vector_type(8))) short short8;
typedef __attribute__((ext_vector_type(4))) float f32x4;

__device__ __forceinline__ unsigned short f2bf(float f) {
    unsigned u = __float_as_uint(f);
    u += 0x7fffu + ((u >> 16) & 1u);          // RNE
    return (unsigned short)(u >> 16);
}
__device__ __forceinline__ float bf2f(unsigned short h) {
    return __uint_as_float(((unsigned)h) << 16);
}

// Pack gw into MFMA-B fragment order, split hi/lo bf16:
// wpk[et][ksg][lane][j] = gw[et*16 + (lane&15)][ksg*32 + (lane>>4)*8 + j]
__global__ __launch_bounds__(256)
void prep_w(const float* __restrict__ gw, unsigned short* __restrict__ wph,
            unsigned short* __restrict__ wpl, int* __restrict__ cnt) {
    const int gid  = blockIdx.x * 256 + threadIdx.x;   // 16384 threads
    const int lane = gid & 63;
    const int ksg  = (gid >> 6) & 63;
    const int et   = gid >> 12;
    const int e    = et * 16 + (lane & 15);
    const int k0   = ksg * 32 + (lane >> 4) * 8;

    float4 v0 = *(const float4*)(gw + (size_t)e * DIM + k0);
    float4 v1 = *(const float4*)(gw + (size_t)e * DIM + k0 + 4);
    float xf[8] = {v0.x, v0.y, v0.z, v0.w, v1.x, v1.y, v1.z, v1.w};
    short8 h, l;
#pragma unroll
    for (int j = 0; j < 8; ++j) {
        unsigned short hh = f2bf(xf[j]);
        h[j] = (short)hh;
        l[j] = (short)f2bf(xf[j] - bf2f(hh));
    }
    *(short8*)(wph + (size_t)gid * 8) = h;
    *(short8*)(wpl + (size_t)gid * 8) = l;
    if (gid == 0) *cnt = 0;
}

__global__ __launch_bounds__(256, 4)
void router_mfma(const float* __restrict__ x,
                 const unsigned short* __restrict__ wph,
                 const unsigned short* __restrict__ wpl,
                 float* __restrict__ out,
                 int* __restrict__ cnt, int* __restrict__ list) {
    __shared__ unsigned short lh[2][8][64][8];   // 16 KB: A-frag hi, 2 bufs
    __shared__ unsigned short llo[2][8][64][8];  // 16 KB: A-frag lo
    __shared__ float lm[16][68];                 // 4.3 KB: merged logits

    const int tid  = threadIdx.x;
    const int lane = tid & 63;
    const int et   = tid >> 6;                   // wave == 16-expert tile
    const int t0   = blockIdx.x * 16;

    // staging map: thread (r = row 0..15, q = 0..15); iter i loads
    // x[t0+r][c*256 + i*64 + q*4 .. +4)  (16 threads = contiguous 256 B)
    const int r  = tid >> 4;
    const int q  = tid & 15;
    const int lw = (((q >> 1) & 3) << 4) | r;    // frag lane
    const int j0 = (q & 1) * 4;                  // frag j-offset
    const float* xrow = x + (size_t)(t0 + r) * DIM;

    float4 st[4];
#define LOADX(c_) { _Pragma("unroll") for (int i = 0; i < 4; ++i) \
        st[i] = *(const float4*)(xrow + (c_) * CHUNK + i * 64 + q * 4); }
#define CVTW(b_) { _Pragma("unroll") for (int i = 0; i < 4; ++i) { \
        const int ks_ = i * 2 + (q >> 3); \
        float xf[4] = {st[i].x, st[i].y, st[i].z, st[i].w}; \
        ushort4 hv, lv; \
        unsigned short t0_ = f2bf(xf[0]); hv.x = t0_; lv.x = f2bf(xf[0] - bf2f(t0_)); \
        unsigned short t1_ = f2bf(xf[1]); hv.y = t1_; lv.y = f2bf(xf[1] - bf2f(t1_)); \
        unsigned short t2_ = f2bf(xf[2]); hv.z = t2_; lv.z = f2bf(xf[2] - bf2f(t2_)); \
        unsigned short t3_ = f2bf(xf[3]); hv.w = t3_; lv.w = f2bf(xf[3] - bf2f(t3_)); \
        *(ushort4*)&lh[b_][ks_][lw][j0]  = hv; \
        *(ushort4*)&llo[b_][ks_][lw][j0] = lv; } }

    LOADX(0)
    CVTW(0)
    __syncthreads();

    f32x4 aA, aB, aC;
#pragma unroll
    for (int j = 0; j < 4; ++j) { aA[j] = 0.f; aB[j] = 0.f; aC[j] = 0.f; }

    const unsigned short* wph_p = wph + (((size_t)et * 64) * 64 + lane) * 8;
    const unsigned short* wpl_p = wpl + (((size_t)et * 64) * 64 + lane) * 8;

    for (int c = 0; c < NCH; ++c) {
        if (c + 1 < NCH) LOADX(c + 1)
        const int cur = c & 1;
#pragma unroll
        for (int ks = 0; ks < 8; ++ks) {
            const int ksg = c * 8 + ks;
            short8 Ah = *(const short8*)&lh[cur][ks][lane][0];
            short8 Al = *(const short8*)&llo[cur][ks][lane][0];
            short8 Bh = *(const short8*)(wph_p + (size_t)ksg * 512);
            short8 Bl = *(const short8*)(wpl_p + (size_t)ksg * 512);
            aA = __builtin_amdgcn_mfma_f32_16x16x32_bf16(Ah, Bh, aA, 0, 0, 0);
            aB = __builtin_amdgcn_mfma_f32_16x16x32_bf16(Ah, Bl, aB, 0, 0, 0);
            aC = __builtin_amdgcn_mfma_f32_16x16x32_bf16(Al, Bh, aC, 0, 0, 0);
        }
        if (c + 1 < NCH) {
            __syncthreads();
            CVTW((c + 1) & 1)
            __syncthreads();
        }
    }
#undef LOADX
#undef CVTW

    // merged logits -> LDS: D layout col(expert)=lane&15, row(token)=(lane>>4)*4+jr
#pragma unroll
    for (int jr = 0; jr < 4; ++jr)
        lm[(lane >> 4) * 4 + jr][et * 16 + (lane & 15)] = aA[jr] + aB[jr] + aC[jr];
    __syncthreads();

    // ---- epilogue: 16 threads per token, 4 experts each ----
    float* mout = out;
    float* wout = out + (size_t)NT * NE;
    float* iout = wout + (size_t)NT * 2;

    const int t   = tid >> 4;
    const int s   = tid & 15;
    const int tok = t0 + t;

    float4 pv = *(const float4*)&lm[t][s * 4];
    float vv[4] = {pv.x, pv.y, pv.z, pv.w};

    float m1 = -FLT_MAX, m2 = -FLT_MAX, m3 = -FLT_MAX;
    int   i1 = NE, i2 = NE, i3 = NE;
    auto ins = [&](float v, int e) {
        bool b1 = (v > m1) || (v == m1 && e < i1);
        bool b2 = (v > m2) || (v == m2 && e < i2);
        bool b3 = (v > m3) || (v == m3 && e < i3);
        if (b1)      { m3 = m2; i3 = i2; m2 = m1; i2 = i1; m1 = v; i1 = e; }
        else if (b2) { m3 = m2; i3 = i2; m2 = v; i2 = e; }
        else if (b3) { m3 = v; i3 = e; }
    };
#pragma unroll
    for (int j = 0; j < 4; ++j) ins(vv[j], s * 4 + j);
#pragma unroll
    for (int off = 1; off <= 8; off <<= 1) {
        float om1 = __shfl_xor(m1, off, 64); int oi1 = __shfl_xor(i1, off, 64);
        float om2 = __shfl_xor(m2, off, 64); int oi2 = __shfl_xor(i2, off, 64);
        float om3 = __shfl_xor(m3, off, 64); int oi3 = __shfl_xor(i3, off, 64);
        ins(om1, oi1); ins(om2, oi2); ins(om3, oi3);
    }

    float ed  = expf(m2 - m1);
    float inv = 1.f / (1.f + ed);

    float4 mv;
    mv.x = (s * 4     == i1 || s * 4     == i2) ? 1.f : 0.f;
    mv.y = (s * 4 + 1 == i1 || s * 4 + 1 == i2) ? 1.f : 0.f;
    mv.z = (s * 4 + 2 == i1 || s * 4 + 2 == i2) ? 1.f : 0.f;
    mv.w = (s * 4 + 3 == i1 || s * 4 + 3 == i2) ? 1.f : 0.f;
    *(float4*)(mout + (size_t)tok * NE + s * 4) = mv;

    if (s == 0) {
        *(float2*)(wout + 2 * tok) = make_float2(inv, ed * inv);
        *(float2*)(iout + 2 * tok) = make_float2((float)i1, (float)i2);
        if ((m1 - m2 < TAU) || (m2 - m3 < TAU)) {
            int slot = atomicAdd(cnt, 1);
            list[slot] = tok;
        }
    }
}

// Exact fp32 recompute of flagged (near-tie) tokens; overwrites their outputs.
__global__ __launch_bounds__(256)
void repair(const float* __restrict__ x, const float* __restrict__ gw,
            float* __restrict__ out, const int* __restrict__ cnt,
            const int* __restrict__ list) {
    __shared__ float red[64][5];
    const int n   = *cnt;
    const int tid = threadIdx.x;
    const int e   = tid & 63, qq = tid >> 6;     // expert, k-quarter

    float* mout = out;
    float* wout = out + (size_t)NT * NE;
    float* iout = wout + (size_t)NT * 2;

    for (int i = blockIdx.x; i < n; i += gridDim.x) {
        const int tok = list[i];
        const float* xr = x + (size_t)tok * DIM + qq * 512;
        const float* wr = gw + (size_t)e * DIM + qq * 512;
        float a = 0.f;
        for (int j = 0; j < 512; j += 4) {
            float4 xv = *(const float4*)(xr + j);
            float4 wv = *(const float4*)(wr + j);
            a = fmaf(xv.x, wv.x, a); a = fmaf(xv.y, wv.y, a);
            a = fmaf(xv.z, wv.z, a); a = fmaf(xv.w, wv.w, a);
        }
        red[e][qq] = a;
        __syncthreads();
        if (tid < 64) {
            float v = ((red[e][0] + red[e][1]) + red[e][2]) + red[e][3];
            float m1 = v, m2 = -FLT_MAX; int i1 = e, i2 = NE;
#pragma unroll
            for (int off = 1; off <= 32; off <<= 1) {
                float om1 = __shfl_xor(m1, off, 64); int oi1 = __shfl_xor(i1, off, 64);
                float om2 = __shfl_xor(m2, off, 64); int oi2 = __shfl_xor(i2, off, 64);
                bool selfFirst = (m1 > om1) || (m1 == om1 && i1 < oi1);
                if (selfFirst) {
                    if (!((m2 > om1) || (m2 == om1 && i2 < oi1))) { m2 = om1; i2 = oi1; }
                } else {
                    bool c = (m1 > om2) || (m1 == om2 && i1 < oi2);
                    if (c) { m2 = m1; i2 = i1; } else { m2 = om2; i2 = oi2; }
                    m1 = om1; i1 = oi1;
                }
            }
            float ed  = expf(m2 - m1);
            float inv = 1.f / (1.f + ed);
            mout[(size_t)tok * NE + e] = (e == i1 || e == i2) ? 1.f : 0.f;
            if (e == 0) {
                *(float2*)(wout + 2 * tok) = make_float2(inv, ed * inv);
                *(float2*)(iout + 2 * tok) = make_float2((float)i1, (float)i2);
            }
        }
        __syncthreads();
    }
}

extern "C" void kernel_launch(void* const* d_in, const int* in_sizes, int n_in,
                              void* d_out, int out_size, void* d_ws, size_t ws_size,
                              hipStream_t stream) {
    const float* x  = (const float*)d_in[0];
    const float* gw = (const float*)d_in[1];
    float* out = (float*)d_out;

    unsigned short* wph = (unsigned short*)d_ws;         // 256 KB (packed hi)
    unsigned short* wpl = wph + (size_t)NE * DIM;        // 256 KB (packed lo)
    int* cnt  = (int*)(wpl + (size_t)NE * DIM);          // 4 B
    int* list = cnt + 1;                                 // 128 KB

    prep_w<<<dim3(64), dim3(256), 0, stream>>>(gw, wph, wpl, cnt);
    router_mfma<<<dim3(NT / 16), dim3(256), 0, stream>>>(x, wph, wpl, out, cnt, list);
    repair<<<dim3(256), dim3(256), 0, stream>>>(x, gw, out, cnt, list);
}

// Round 10
// 95.941 us; speedup vs baseline: 2.2885x; 1.3520x over previous
//
#include <hip/hip_runtime.h>
#include <float.h>

#define NT 32768
#define DIM 2048
#define NE 64
#define TAU 1e-3f
#define CHUNK 128
#define NCH (DIM / CHUNK)   // 16 chunks

typedef __attribute__((ext_vector_type(8))) short short8;
typedef __attribute__((ext_vector_type(4))) float f32x4;

__device__ __forceinline__ unsigned short f2bf(float f) {
    unsigned u = __float_as_uint(f);
    u += 0x7fffu + ((u >> 16) & 1u);          // RNE
    return (unsigned short)(u >> 16);
}
__device__ __forceinline__ float bf2f(unsigned short h) {
    return __uint_as_float(((unsigned)h) << 16);
}

// Pack gw into MFMA-B fragment order, split hi/lo bf16 (RNE):
// wpk[et][ksg][lane][j] = gw[et*16 + (lane&15)][ksg*32 + (lane>>4)*8 + j]
__global__ __launch_bounds__(256)
void prep_w(const float* __restrict__ gw, unsigned short* __restrict__ wph,
            unsigned short* __restrict__ wpl, int* __restrict__ cnt) {
    const int gid  = blockIdx.x * 256 + threadIdx.x;   // 16384 threads
    const int lane = gid & 63;
    const int ksg  = (gid >> 6) & 63;
    const int et   = gid >> 12;
    const int e    = et * 16 + (lane & 15);
    const int k0   = ksg * 32 + (lane >> 4) * 8;

    float4 v0 = *(const float4*)(gw + (size_t)e * DIM + k0);
    float4 v1 = *(const float4*)(gw + (size_t)e * DIM + k0 + 4);
    float xf[8] = {v0.x, v0.y, v0.z, v0.w, v1.x, v1.y, v1.z, v1.w};
    short8 h, l;
#pragma unroll
    for (int j = 0; j < 8; ++j) {
        unsigned short hh = f2bf(xf[j]);
        h[j] = (short)hh;
        l[j] = (short)f2bf(xf[j] - bf2f(hh));
    }
    *(short8*)(wph + (size_t)gid * 8) = h;
    *(short8*)(wpl + (size_t)gid * 8) = l;
    if (gid == 0) *cnt = 0;
}

__global__ __launch_bounds__(256, 2)
void router_mfma(const float* __restrict__ x,
                 const unsigned short* __restrict__ wph,
                 const unsigned short* __restrict__ wpl,
                 float* __restrict__ out,
                 int* __restrict__ cnt, int* __restrict__ list) {
    // 64 KB: 2 dbuf x {hi plane 16K, lo plane 16K}; epilogue aliases float lm[64][68]
    __shared__ __align__(16) unsigned char smem[65536];

    const int tid  = threadIdx.x;
    const int lane = tid & 63;
    const int et   = tid >> 6;                 // wave == 16-expert tile
    const int t0   = blockIdx.x * 64;

    // staging coords: thread (sr = token row 0..15, sq = k-quad 0..15)
    const int sr = tid >> 4;
    const int sq = tid & 15;
    const unsigned swoff = (unsigned)((sr * 128 + sq * 8) ^ ((sr & 7) << 4));
    const float* xbase = x + (size_t)(t0 + sr) * DIM + sq * 4;

    // compute-side swizzled read offsets (ks even / odd)
    const unsigned roff_e = (unsigned)((((lane & 15) * 128) | ((lane >> 4) << 4))
                                       ^ ((lane & 7) << 4));
    const unsigned roff_o = roff_e ^ 64u;

    f32x4 accP[4], accQ[4];
#pragma unroll
    for (int tt = 0; tt < 4; ++tt)
#pragma unroll
        for (int j = 0; j < 4; ++j) { accP[tt][j] = 0.f; accQ[tt][j] = 0.f; }

    float4 xr[8];
    short8 Bh0[4], Bl0[4], Bh1[4], Bl1[4];

#define LOADX(c_) { _Pragma("unroll") for (int tt = 0; tt < 4; ++tt) \
    _Pragma("unroll") for (int i = 0; i < 2; ++i) \
        xr[tt*2+i] = *(const float4*)(xbase + (size_t)tt * 16 * DIM + (c_) * CHUNK + i * 64); }

#define BLOAD(bk_, c_) { _Pragma("unroll") for (int ksg = 0; ksg < 4; ++ksg) { \
        size_t o_ = (((size_t)et * 64 + ((c_) * 4 + ksg)) * 64 + lane) * 8; \
        Bh##bk_[ksg] = *(const short8*)(wph + o_); \
        Bl##bk_[ksg] = *(const short8*)(wpl + o_); } }

// truncation split: hi = top16(x), lo = top16(x - hi)
#define CVT_STORE(buf_) { _Pragma("unroll") for (int tt = 0; tt < 4; ++tt) \
    _Pragma("unroll") for (int i = 0; i < 2; ++i) { \
        float4 v_ = xr[tt*2+i]; \
        unsigned u0 = __float_as_uint(v_.x), u1 = __float_as_uint(v_.y); \
        unsigned u2 = __float_as_uint(v_.z), u3 = __float_as_uint(v_.w); \
        float l0 = v_.x - __uint_as_float(u0 & 0xffff0000u); \
        float l1 = v_.y - __uint_as_float(u1 & 0xffff0000u); \
        float l2 = v_.z - __uint_as_float(u2 & 0xffff0000u); \
        float l3 = v_.w - __uint_as_float(u3 & 0xffff0000u); \
        ushort4 hv_ = make_ushort4((unsigned short)(u0 >> 16), (unsigned short)(u1 >> 16), \
                                   (unsigned short)(u2 >> 16), (unsigned short)(u3 >> 16)); \
        ushort4 lv_ = make_ushort4((unsigned short)(__float_as_uint(l0) >> 16), \
                                   (unsigned short)(__float_as_uint(l1) >> 16), \
                                   (unsigned short)(__float_as_uint(l2) >> 16), \
                                   (unsigned short)(__float_as_uint(l3) >> 16)); \
        unsigned char* p_ = smem + (buf_) * 32768 + (tt*2+i) * 2048 + swoff; \
        *(ushort4*)p_ = hv_; \
        *(ushort4*)(p_ + 16384) = lv_; } }

#define MFMA_PHASE(buf_, bk_) { _Pragma("unroll") for (int ks = 0; ks < 4; ++ks) { \
        const unsigned ro_ = (ks & 1) ? roff_o : roff_e; \
        _Pragma("unroll") for (int tt = 0; tt < 4; ++tt) { \
            const unsigned char* pa_ = smem + (buf_) * 32768 + tt * 4096 + (ks >> 1) * 2048 + ro_; \
            short8 Ah_ = *(const short8*)pa_; \
            short8 Al_ = *(const short8*)(pa_ + 16384); \
            accP[tt] = __builtin_amdgcn_mfma_f32_16x16x32_bf16(Ah_, Bh##bk_[ks], accP[tt], 0, 0, 0); \
            accQ[tt] = __builtin_amdgcn_mfma_f32_16x16x32_bf16(Ah_, Bl##bk_[ks], accQ[tt], 0, 0, 0); \
            accQ[tt] = __builtin_amdgcn_mfma_f32_16x16x32_bf16(Al_, Bh##bk_[ks], accQ[tt], 0, 0, 0); } } }

#define STEP(c_, bufc_, bufn_, bkn_) { \
        if ((c_) < NCH - 1) { LOADX((c_) + 1) BLOAD(bkn_, (c_) + 1) } \
        MFMA_PHASE(bufc_, bufc_) \
        if ((c_) < NCH - 1) { CVT_STORE(bufn_) } \
        __syncthreads(); }

    // prologue: chunk 0 staged, B(0) in bank 0
    LOADX(0)
    BLOAD(0, 0)
    CVT_STORE(0)
    __syncthreads();

#pragma unroll 1
    for (int cc = 0; cc < NCH / 2; ++cc) {
        STEP(2 * cc,     0, 1, 1)
        STEP(2 * cc + 1, 1, 0, 0)
    }
#undef LOADX
#undef BLOAD
#undef CVT_STORE
#undef MFMA_PHASE
#undef STEP

    // merge logits into aliased LDS (buffers dead after final sync in STEP)
    float* lmf = (float*)smem;                 // [64][68]
#pragma unroll
    for (int tt = 0; tt < 4; ++tt)
#pragma unroll
        for (int jr = 0; jr < 4; ++jr)
            lmf[(tt * 16 + (lane >> 4) * 4 + jr) * 68 + et * 16 + (lane & 15)] =
                accP[tt][jr] + accQ[tt][jr];
    __syncthreads();

    // ---- epilogue: 4 threads per token, 16 experts each ----
    float* mout = out;
    float* wout = out + (size_t)NT * NE;
    float* iout = wout + (size_t)NT * 2;

    const int t   = tid >> 2;                  // local token 0..63
    const int s   = tid & 3;                   // 16-expert segment
    const int tok = t0 + t;

    float vv[16];
#pragma unroll
    for (int j4 = 0; j4 < 4; ++j4) {
        float4 pv = *(const float4*)&lmf[t * 68 + s * 16 + j4 * 4];
        vv[j4 * 4] = pv.x; vv[j4 * 4 + 1] = pv.y; vv[j4 * 4 + 2] = pv.z; vv[j4 * 4 + 3] = pv.w;
    }

    float m1 = -FLT_MAX, m2 = -FLT_MAX, m3 = -FLT_MAX;
    int   i1 = NE, i2 = NE, i3 = NE;
    auto ins = [&](float v, int e) {
        bool b1 = (v > m1) || (v == m1 && e < i1);
        bool b2 = (v > m2) || (v == m2 && e < i2);
        bool b3 = (v > m3) || (v == m3 && e < i3);
        if (b1)      { m3 = m2; i3 = i2; m2 = m1; i2 = i1; m1 = v; i1 = e; }
        else if (b2) { m3 = m2; i3 = i2; m2 = v; i2 = e; }
        else if (b3) { m3 = v; i3 = e; }
    };
#pragma unroll
    for (int j = 0; j < 16; ++j) ins(vv[j], s * 16 + j);
#pragma unroll
    for (int off = 1; off <= 2; off <<= 1) {   // merge across the 4-lane group
        float om1 = __shfl_xor(m1, off, 64); int oi1 = __shfl_xor(i1, off, 64);
        float om2 = __shfl_xor(m2, off, 64); int oi2 = __shfl_xor(i2, off, 64);
        float om3 = __shfl_xor(m3, off, 64); int oi3 = __shfl_xor(i3, off, 64);
        ins(om1, oi1); ins(om2, oi2); ins(om3, oi3);
    }

    float ed  = expf(m2 - m1);
    float inv = 1.f / (1.f + ed);

#pragma unroll
    for (int j4 = 0; j4 < 4; ++j4) {
        float4 mv;
        int e0 = s * 16 + j4 * 4;
        mv.x = (e0     == i1 || e0     == i2) ? 1.f : 0.f;
        mv.y = (e0 + 1 == i1 || e0 + 1 == i2) ? 1.f : 0.f;
        mv.z = (e0 + 2 == i1 || e0 + 2 == i2) ? 1.f : 0.f;
        mv.w = (e0 + 3 == i1 || e0 + 3 == i2) ? 1.f : 0.f;
        *(float4*)(mout + (size_t)tok * NE + e0) = mv;
    }

    if (s == 0) {
        *(float2*)(wout + 2 * tok) = make_float2(inv, ed * inv);
        *(float2*)(iout + 2 * tok) = make_float2((float)i1, (float)i2);
        if ((m1 - m2 < TAU) || (m2 - m3 < TAU)) {
            int slot = atomicAdd(cnt, 1);
            list[slot] = tok;
        }
    }
}

// Exact fp32 recompute of flagged (near-tie) tokens; overwrites their outputs.
__global__ __launch_bounds__(256)
void repair(const float* __restrict__ x, const float* __restrict__ gw,
            float* __restrict__ out, const int* __restrict__ cnt,
            const int* __restrict__ list) {
    __shared__ float red[64][5];
    const int n   = *cnt;
    const int tid = threadIdx.x;
    const int e   = tid & 63, qq = tid >> 6;     // expert, k-quarter

    float* mout = out;
    float* wout = out + (size_t)NT * NE;
    float* iout = wout + (size_t)NT * 2;

    for (int i = blockIdx.x; i < n; i += gridDim.x) {
        const int tok = list[i];
        const float* xr = x + (size_t)tok * DIM + qq * 512;
        const float* wr = gw + (size_t)e * DIM + qq * 512;
        float a = 0.f;
        for (int j = 0; j < 512; j += 4) {
            float4 xv = *(const float4*)(xr + j);
            float4 wv = *(const float4*)(wr + j);
            a = fmaf(xv.x, wv.x, a); a = fmaf(xv.y, wv.y, a);
            a = fmaf(xv.z, wv.z, a); a = fmaf(xv.w, wv.w, a);
        }
        red[e][qq] = a;
        __syncthreads();
        if (tid < 64) {
            float v = ((red[e][0] + red[e][1]) + red[e][2]) + red[e][3];
            float m1 = v, m2 = -FLT_MAX; int i1 = e, i2 = NE;
#pragma unroll
            for (int off = 1; off <= 32; off <<= 1) {
                float om1 = __shfl_xor(m1, off, 64); int oi1 = __shfl_xor(i1, off, 64);
                float om2 = __shfl_xor(m2, off, 64); int oi2 = __shfl_xor(i2, off, 64);
                bool selfFirst = (m1 > om1) || (m1 == om1 && i1 < oi1);
                if (selfFirst) {
                    if (!((m2 > om1) || (m2 == om1 && i2 < oi1))) { m2 = om1; i2 = oi1; }
                } else {
                    bool c = (m1 > om2) || (m1 == om2 && i1 < oi2);
                    if (c) { m2 = m1; i2 = i1; } else { m2 = om2; i2 = oi2; }
                    m1 = om1; i1 = oi1;
                }
            }
            float ed  = expf(m2 - m1);
            float inv = 1.f / (1.f + ed);
            mout[(size_t)tok * NE + e] = (e == i1 || e == i2) ? 1.f : 0.f;
            if (e == 0) {
                *(float2*)(wout + 2 * tok) = make_float2(inv, ed * inv);
                *(float2*)(iout + 2 * tok) = make_float2((float)i1, (float)i2);
            }
        }
        __syncthreads();
    }
}

extern "C" void kernel_launch(void* const* d_in, const int* in_sizes, int n_in,
                              void* d_out, int out_size, void* d_ws, size_t ws_size,
                              hipStream_t stream) {
    const float* x  = (const float*)d_in[0];
    const float* gw = (const float*)d_in[1];
    float* out = (float*)d_out;

    unsigned short* wph = (unsigned short*)d_ws;         // 256 KB (packed hi)
    unsigned short* wpl = wph + (size_t)NE * DIM;        // 256 KB (packed lo)
    int* cnt  = (int*)(wpl + (size_t)NE * DIM);          // 4 B
    int* list = cnt + 1;                                 // 128 KB

    prep_w<<<dim3(64), dim3(256), 0, stream>>>(gw, wph, wpl, cnt);
    router_mfma<<<dim3(NT / 64), dim3(256), 0, stream>>>(x, wph, wpl, out, cnt, list);
    repair<<<dim3(256), dim3(256), 0, stream>>>(x, gw, out, cnt, list);
}